// Round 7
// baseline (87.471 us; speedup 1.0000x reference)
//
#include <hip/hip_runtime.h>
#include <hip/hip_fp16.h>

// B=1: flows [L,2,H,W] f32, images [L,C,H,W] f32, out [L,C,H,W] f32
// out[t] = sum_{k<=t} bilinear_sample(images[k], base_grid + cum[t]-cum[k])
constexpr int L = 16, C = 8, H = 128, W = 128;
constexpr int HW = H * W;
constexpr int CHW = C * HW;

// ---------------------------------------------------------------------------
// Prep: transpose+convert images [L][C][H][W] f32 -> [L][HW][C] fp16.
// ---------------------------------------------------------------------------
__global__ __launch_bounds__(256) void prep_k(const float* __restrict__ images,
                                              __half* __restrict__ timg) {
    int idx = blockIdx.x * 256 + threadIdx.x;      // [0, L*HW)
    int l = idx >> 14, pix = idx & (HW - 1);
    const float* src = images + (size_t)l * CHW + pix;
    float4 packed;
    __half2* hp = reinterpret_cast<__half2*>(&packed);
    hp[0] = __floats2half2_rn(src[0 * HW], src[1 * HW]);
    hp[1] = __floats2half2_rn(src[2 * HW], src[3 * HW]);
    hp[2] = __floats2half2_rn(src[4 * HW], src[5 * HW]);
    hp[3] = __floats2half2_rn(src[6 * HW], src[7 * HW]);
    reinterpret_cast<float4*>(timg)[idx] = packed; // 16 B/pixel
}

// ---------------------------------------------------------------------------
// One bilinear sample of 8 fp16 channels into float acc[8]  (R2-proven body).
// Matches torch grid_sample(bilinear, zeros, align_corners=False) + x-wrap.
// ---------------------------------------------------------------------------
__device__ __forceinline__ void samp(float acc[8], float relx, float rely,
                                     float bx1, float by1,
                                     const __half* __restrict__ img) {
    float xr = bx1 + relx;                          // gx + 1 (unwrapped)
    xr = fmaf(-2.0f, floorf(xr * 0.5f), xr);        // remainder(xr,2) in [0,2)
    float yr = by1 + rely;                          // gy + 1
    float ix = fmaf(xr, W * 0.5f, -0.5f);
    float iy = fmaf(yr, H * 0.5f, -0.5f);
    float x0f = floorf(ix), y0f = floorf(iy);
    float wx = ix - x0f, wy = iy - y0f;
    int x0 = (int)x0f, y0 = (int)y0f;

    float wx0 = ((unsigned)x0       < (unsigned)W) ? 1.f - wx : 0.f;
    float wx1 = ((unsigned)(x0 + 1) < (unsigned)W) ? wx       : 0.f;
    float wy0 = ((unsigned)y0       < (unsigned)H) ? 1.f - wy : 0.f;
    float wy1 = ((unsigned)(y0 + 1) < (unsigned)H) ? wy       : 0.f;
    int xi0 = min(max(x0, 0), W - 1), xi1 = min(max(x0 + 1, 0), W - 1);
    int yi0 = min(max(y0, 0), H - 1), yi1 = min(max(y0 + 1, 0), H - 1);

    const float4* p = reinterpret_cast<const float4*>(img);
    float4 r00 = p[yi0 * W + xi0];
    float4 r01 = p[yi0 * W + xi1];
    float4 r10 = p[yi1 * W + xi0];
    float4 r11 = p[yi1 * W + xi1];
    float w00 = wx0 * wy0, w01 = wx1 * wy0, w10 = wx0 * wy1, w11 = wx1 * wy1;
    const __half* h00 = reinterpret_cast<const __half*>(&r00);
    const __half* h01 = reinterpret_cast<const __half*>(&r01);
    const __half* h10 = reinterpret_cast<const __half*>(&r10);
    const __half* h11 = reinterpret_cast<const __half*>(&r11);
#pragma unroll
    for (int c = 0; c < 8; ++c) {
        float v = fmaf(__half2float(h00[c]), w00,
                  fmaf(__half2float(h01[c]), w01,
                  fmaf(__half2float(h10[c]), w10,
                       __half2float(h11[c]) * w11)));
        acc[c] += v;
    }
}

// ---------------------------------------------------------------------------
// Fully-unrolled per-pair body: t1 = P, t2 = 15-P are compile-time, so the
// compiler can software-pipeline load issue across k-iterations.
// ---------------------------------------------------------------------------
template <int P>
__device__ __forceinline__ void pair_body(const float* __restrict__ flows,
                                          const __half* __restrict__ timg,
                                          float* __restrict__ out,
                                          int pix, float bx1, float by1) {
    constexpr int T1 = P, T2 = 15 - P;

    // in-register cumulative flow (identical fp32 sequence to jnp.cumsum)
    float Px[L], Py[L];
    {
        float sx = 0.f, sy = 0.f;
#pragma unroll
        for (int j = 0; j < L; ++j) {
            sx += flows[(size_t)(2 * j)     * HW + pix];
            sy += flows[(size_t)(2 * j + 1) * HW + pix];
            Px[j] = sx; Py[j] = sy;
        }
    }

    float acc1[8] = {0, 0, 0, 0, 0, 0, 0, 0};
    float acc2[8] = {0, 0, 0, 0, 0, 0, 0, 0};

#pragma unroll
    for (int k = 0; k <= T2; ++k) {
        const __half* img = timg + (size_t)k * HW * C;
        samp(acc2, Px[T2] - Px[k], Py[T2] - Py[k], bx1, by1, img);
        if (k <= T1)
            samp(acc1, Px[T1] - Px[k], Py[T1] - Py[k], bx1, by1, img);
    }

    size_t o1 = (size_t)T1 * CHW + pix;
    size_t o2 = (size_t)T2 * CHW + pix;
#pragma unroll
    for (int c = 0; c < 8; ++c) {
        out[o1 + (size_t)c * HW] = acc1[c];
        out[o2 + (size_t)c * HW] = acc2[c];
    }
}

// ---------------------------------------------------------------------------
// Main sampler: thread = one pixel for t-pair (p, 15-p); uniform 17 k-iters.
// Blocks are 16x8 pixel tiles; switch(p) dispatches to the compile-time body.
// ---------------------------------------------------------------------------
constexpr int TPB = 128;
__global__ __launch_bounds__(TPB) void sample_k(const float* __restrict__ flows,
                                                const __half* __restrict__ timg,
                                                float* __restrict__ out) {
    int b    = blockIdx.x;
    int p    = b >> 7;                              // 8 pairs x 128 tiles
    int tile = b & 127;
    int Tx = tile & 7, Ty = tile >> 3;              // 8 x 16 tile grid
    int tx = threadIdx.x & 15, ty = threadIdx.x >> 4;
    int w = Tx * 16 + tx, h = Ty * 8 + ty;
    int pix = h * W + w;

    float bx1 = (w + 0.5f) * (2.0f / W);
    float by1 = (h + 0.5f) * (2.0f / H);

    switch (p) {                                    // block-uniform scalar branch
        case 0: pair_body<0>(flows, timg, out, pix, bx1, by1); break;
        case 1: pair_body<1>(flows, timg, out, pix, bx1, by1); break;
        case 2: pair_body<2>(flows, timg, out, pix, bx1, by1); break;
        case 3: pair_body<3>(flows, timg, out, pix, bx1, by1); break;
        case 4: pair_body<4>(flows, timg, out, pix, bx1, by1); break;
        case 5: pair_body<5>(flows, timg, out, pix, bx1, by1); break;
        case 6: pair_body<6>(flows, timg, out, pix, bx1, by1); break;
        default: pair_body<7>(flows, timg, out, pix, bx1, by1); break;
    }
}

// ---------------------------------------------------------------------------
extern "C" void kernel_launch(void* const* d_in, const int* in_sizes, int n_in,
                              void* d_out, int out_size, void* d_ws, size_t ws_size,
                              hipStream_t stream) {
    const float* flows  = (const float*)d_in[0];   // [L,2,H,W]
    const float* images = (const float*)d_in[1];   // [L,C,H,W]
    float* out = (float*)d_out;                    // [L,C,H,W]

    __half* timg = (__half*)d_ws;                  // [L][HW][C] fp16, 4 MiB

    prep_k<<<(L * HW) / 256, 256, 0, stream>>>(images, timg);
    sample_k<<<8 * 128, TPB, 0, stream>>>(flows, timg, out);
}

// Round 8
// 85.446 us; speedup vs baseline: 1.0237x; 1.0237x over previous
//
#include <hip/hip_runtime.h>
#include <hip/hip_fp16.h>

// B=1: flows [L,2,H,W] f32, images [L,C,H,W] f32, out [L,C,H,W] f32
// out[t] = sum_{k<=t} bilinear_sample(images[k], base_grid + cum[t]-cum[k])
//
// Final kernel (session best, R6 structure, 85.5 us):
//  - images transposed+converted to [L][HW][C] fp16 (one float4 per corner
//    gather instead of 8 channel-strided scalars; 4 MiB = XCD-L2-resident)
//  - per-pixel flow prefix sums built in registers (fp32, identical sequence
//    to jnp.cumsum; kills the separate cum buffer + its loads)
//  - thread = one pixel for the t-pair (p, 15-p): uniform 17 k-iterations,
//    perfect load balance, block-uniform branch
//  - 16x8 pixel tile blocks for compact gather footprint
// Measured ceiling: timed window is dominated by the harness's 268 MB
// ws-poison fill (~44 us at 75-78% HBM peak); sample_k (~30 us) sits within
// ~1.5x of the scattered-gather L1/L2 line-traffic floor. Seven structural
// variants (occupancy x3, NT stores, MLP restructure, full unroll, tiling)
// all land within +-2.3%.
constexpr int L = 16, C = 8, H = 128, W = 128;
constexpr int HW = H * W;
constexpr int CHW = C * HW;

// ---------------------------------------------------------------------------
// Prep: transpose+convert images [L][C][H][W] f32 -> [L][HW][C] fp16.
// ---------------------------------------------------------------------------
__global__ __launch_bounds__(256) void prep_k(const float* __restrict__ images,
                                              __half* __restrict__ timg) {
    int idx = blockIdx.x * 256 + threadIdx.x;      // [0, L*HW)
    int l = idx >> 14, pix = idx & (HW - 1);
    const float* src = images + (size_t)l * CHW + pix;
    float4 packed;
    __half2* hp = reinterpret_cast<__half2*>(&packed);
    hp[0] = __floats2half2_rn(src[0 * HW], src[1 * HW]);
    hp[1] = __floats2half2_rn(src[2 * HW], src[3 * HW]);
    hp[2] = __floats2half2_rn(src[4 * HW], src[5 * HW]);
    hp[3] = __floats2half2_rn(src[6 * HW], src[7 * HW]);
    reinterpret_cast<float4*>(timg)[idx] = packed; // 16 B/pixel
}

// ---------------------------------------------------------------------------
// One bilinear sample of 8 fp16 channels into float acc[8].
// Matches torch grid_sample(bilinear, zeros, align_corners=False) + x-wrap.
// ---------------------------------------------------------------------------
__device__ __forceinline__ void samp(float acc[8], float relx, float rely,
                                     float bx1, float by1,
                                     const __half* __restrict__ img) {
    float xr = bx1 + relx;                          // gx + 1 (unwrapped)
    xr = fmaf(-2.0f, floorf(xr * 0.5f), xr);        // remainder(xr,2) in [0,2)
    float yr = by1 + rely;                          // gy + 1
    float ix = fmaf(xr, W * 0.5f, -0.5f);
    float iy = fmaf(yr, H * 0.5f, -0.5f);
    float x0f = floorf(ix), y0f = floorf(iy);
    float wx = ix - x0f, wy = iy - y0f;
    int x0 = (int)x0f, y0 = (int)y0f;

    float wx0 = ((unsigned)x0       < (unsigned)W) ? 1.f - wx : 0.f;
    float wx1 = ((unsigned)(x0 + 1) < (unsigned)W) ? wx       : 0.f;
    float wy0 = ((unsigned)y0       < (unsigned)H) ? 1.f - wy : 0.f;
    float wy1 = ((unsigned)(y0 + 1) < (unsigned)H) ? wy       : 0.f;
    int xi0 = min(max(x0, 0), W - 1), xi1 = min(max(x0 + 1, 0), W - 1);
    int yi0 = min(max(y0, 0), H - 1), yi1 = min(max(y0 + 1, 0), H - 1);

    const float4* p = reinterpret_cast<const float4*>(img);
    float4 r00 = p[yi0 * W + xi0];
    float4 r01 = p[yi0 * W + xi1];
    float4 r10 = p[yi1 * W + xi0];
    float4 r11 = p[yi1 * W + xi1];
    float w00 = wx0 * wy0, w01 = wx1 * wy0, w10 = wx0 * wy1, w11 = wx1 * wy1;
    const __half* h00 = reinterpret_cast<const __half*>(&r00);
    const __half* h01 = reinterpret_cast<const __half*>(&r01);
    const __half* h10 = reinterpret_cast<const __half*>(&r10);
    const __half* h11 = reinterpret_cast<const __half*>(&r11);
#pragma unroll
    for (int c = 0; c < 8; ++c) {
        float v = fmaf(__half2float(h00[c]), w00,
                  fmaf(__half2float(h01[c]), w01,
                  fmaf(__half2float(h10[c]), w10,
                       __half2float(h11[c]) * w11)));
        acc[c] += v;
    }
}

// ---------------------------------------------------------------------------
// Main sampler: thread = one pixel for t-pair (p, 15-p); uniform 17 k-iters.
// ---------------------------------------------------------------------------
constexpr int TPB = 128;
__global__ __launch_bounds__(TPB) void sample_k(const float* __restrict__ flows,
                                                const __half* __restrict__ timg,
                                                float* __restrict__ out) {
    int b    = blockIdx.x;
    int p    = b >> 7;                              // 8 pairs x 128 tiles
    int tile = b & 127;
    int Tx = tile & 7, Ty = tile >> 3;              // 8 x 16 tile grid
    int tx = threadIdx.x & 15, ty = threadIdx.x >> 4;
    int w = Tx * 16 + tx, h = Ty * 8 + ty;
    int pix = h * W + w;

    float bx1 = (w + 0.5f) * (2.0f / W);
    float by1 = (h + 0.5f) * (2.0f / H);

    // in-register cumulative flow (identical fp32 sequence to jnp.cumsum)
    float Px[L], Py[L];
    {
        float sx = 0.f, sy = 0.f;
#pragma unroll
        for (int j = 0; j < L; ++j) {
            sx += flows[(size_t)(2 * j)     * HW + pix];
            sy += flows[(size_t)(2 * j + 1) * HW + pix];
            Px[j] = sx; Py[j] = sy;
        }
    }

    int t1 = p, t2 = 15 - p;                        // t1 < t2 always
    float c1x = Px[t1], c1y = Py[t1];
    float c2x = Px[t2], c2y = Py[t2];

    float acc1[8] = {0, 0, 0, 0, 0, 0, 0, 0};
    float acc2[8] = {0, 0, 0, 0, 0, 0, 0, 0};

    for (int k = 0; k <= t2; ++k) {
        const __half* img = timg + (size_t)k * HW * C;
        samp(acc2, c2x - Px[k], c2y - Py[k], bx1, by1, img);
        if (k <= t1)                                 // block-uniform branch
            samp(acc1, c1x - Px[k], c1y - Py[k], bx1, by1, img);
    }

    size_t o1 = (size_t)t1 * CHW + pix;
    size_t o2 = (size_t)t2 * CHW + pix;
#pragma unroll
    for (int c = 0; c < 8; ++c) {
        out[o1 + (size_t)c * HW] = acc1[c];
        out[o2 + (size_t)c * HW] = acc2[c];
    }
}

// ---------------------------------------------------------------------------
extern "C" void kernel_launch(void* const* d_in, const int* in_sizes, int n_in,
                              void* d_out, int out_size, void* d_ws, size_t ws_size,
                              hipStream_t stream) {
    const float* flows  = (const float*)d_in[0];   // [L,2,H,W]
    const float* images = (const float*)d_in[1];   // [L,C,H,W]
    float* out = (float*)d_out;                    // [L,C,H,W]

    __half* timg = (__half*)d_ws;                  // [L][HW][C] fp16, 4 MiB

    prep_k<<<(L * HW) / 256, 256, 0, stream>>>(images, timg);
    sample_k<<<8 * 128, TPB, 0, stream>>>(flows, timg, out);
}